// Round 10
// baseline (163.896 us; speedup 1.0000x reference)
//
#include <hip/hip_runtime.h>
#include <stdint.h>

// Problem constants: B=32, L=8192, C=64, M=64. All I/O fp32.
#define L_     8192
#define NB     32
#define NC     64
#define SPLITK 16
#define CHUNK  (L_ / SPLITK)   // 512
#define SXPAD  520             // LDS row stride (bf16 elems): 512 + 8 pad

// d_out (64 MiB fp32) is scratch for k1/k1b; k3 overwrites all of it and
// reads none of it. TF lives in d_ws (proven writable, >=2 MiB, by round-5's
// passing run), so the wr input buffer is never modified on the main path.
#define XF_OFF  0            // XF partials: 16 x 32 x 8192 fp32 = 16 MiB
#define XR_OFF  (16u << 20)  // XF reduced:  32 x 8192 fp32 = 1 MiB  [c][j] layout
#define WC_OFF  (17u << 20)  // wr copy (fallback path only): 1 MiB

typedef __bf16 bf16x8 __attribute__((ext_vector_type(8)));
typedef float  f32x4  __attribute__((ext_vector_type(4)));

__device__ __forceinline__ unsigned short f2bf(float f) {
  union { float f; unsigned int i; } v; v.f = f;
  unsigned int r = v.i + 0x7fffu + ((v.i >> 16) & 1u);  // RNE (cold paths)
  return (unsigned short)(r >> 16);
}
__device__ __forceinline__ f32x4 mfma16(bf16x8 a, bf16x8 b, f32x4 c) {
  return __builtin_amdgcn_mfma_f32_16x16x32_bf16(a, b, c, 0, 0, 0);
}

// ---------------------------------------------------------------------------
// k1 v8: round-4 shape (512 blocks, 16 slabs, 66.5 KiB LDS), but the forward
// DFT basis A-frags are generated IN-REGISTER instead of loaded from a k0
// table: Bf[j][l] = a_k * cos(2pi*((k*l + 2048*(j&1)) mod 8192)/8192), using
// -sin(t) = cos(t + pi/2) so odd rows need no separate path. One __cosf per
// element (~256 trans ops/wave/k-loop) rides the idle trans pipe and replaces
// the 2 per-k-step global loads (the same latency pattern that hurt k3 v2).
// k0 is deleted entirely.
// ---------------------------------------------------------------------------
__global__ __launch_bounds__(256) void k1_dft(const float* __restrict__ x,
                                              float* __restrict__ XFP) {
  const int b = blockIdx.x >> 4;
  const int p = blockIdx.x & 15;
  const int l0 = p * CHUNK;
  const int t = threadIdx.x;
  const int wv = t >> 6, lane = t & 63, q = lane >> 4, n = lane & 15;
  __shared__ uint32_t sx[NC * SXPAD / 2];   // [c][l] bf16, l-pairs packed
  const float* xb = x + (size_t)b * L_ * NC;

  {                                          // stage + transpose (round-4 map)
    const int g  = t & 15;                   // channel group (4 ch)
    const int r2 = t >> 4;                   // row-pair 0..15
    for (int s = 0; s < 16; ++s) {           // 16 batches of 32 l-rows
      const int lrow = s * 32 + 2 * r2;
      const f32x4 u0 = *(const f32x4*)(xb + (size_t)(l0 + lrow) * NC + 4 * g);
      const f32x4 u1 = *(const f32x4*)(xb + (size_t)(l0 + lrow + 1) * NC + 4 * g);
      #pragma unroll
      for (int jj = 0; jj < 4; ++jj) {
        __bf16 pk2[2] = {(__bf16)u0[jj], (__bf16)u1[jj]};
        sx[(4 * g + jj) * (SXPAD / 2) + s * 16 + r2] = __builtin_bit_cast(uint32_t, pk2);
      }
    }
  }
  __syncthreads();

  f32x4 acc[2][4];
  #pragma unroll
  for (int i = 0; i < 2; ++i)
    #pragma unroll
    for (int jn = 0; jn < 4; ++jn) acc[i][jn] = (f32x4){0.f, 0.f, 0.f, 0.f};
  const unsigned short* sxu = (const unsigned short*)sx;

  // per-thread basis-row constants: rows r0 = wv*32+n and r0+16 (same parity)
  const float W0 = 6.283185307179586f / 8192.0f;
  const int r0  = wv * 32 + n;
  const int kr0 = r0 >> 1;                  // mode of row r0
  const int kr1 = kr0 + 8;                  // mode of row r0+16 (never 0)
  const int off = (r0 & 1) << 11;           // +2048 phase: cos -> -sin rows
  const float a0s = (kr0 == 0 ? 1.0f : 2.0f) * (1.0f / 8192.0f);
  const float a1s = 2.0f * (1.0f / 8192.0f);

  for (int ks = 0; ks < CHUNK; ks += 32) {
    const int lb = ks + q * 8;
    bf16x8 bfr[4];
    #pragma unroll
    for (int nt = 0; nt < 4; ++nt)           // B-frag: 16B LDS reads
      bfr[nt] = *(const bf16x8*)(sxu + (nt * 16 + n) * SXPAD + lb);
    // A-frags in-register (exact int phase, one cos per element)
    const int lbase = l0 + lb;
    bf16x8 a0f, a1f;
    #pragma unroll
    for (int jj = 0; jj < 8; ++jj) {
      a0f[jj] = (__bf16)(a0s * __cosf((float)((kr0 * (lbase + jj) + off) & 8191) * W0));
      a1f[jj] = (__bf16)(a1s * __cosf((float)((kr1 * (lbase + jj) + off) & 8191) * W0));
    }
    #pragma unroll
    for (int nt = 0; nt < 4; ++nt)
      acc[0][nt] = mfma16(a0f, bfr[nt], acc[0][nt]);
    #pragma unroll
    for (int nt = 0; nt < 4; ++nt)
      acc[1][nt] = mfma16(a1f, bfr[nt], acc[1][nt]);
  }

  // D layout: row(M)=mode j = wv*32+mt*16+q*4+r, col(N)=c = nt*16+n.
  // Store transposed [c][j]: r walks contiguous j -> f32x4 stores.
  float* op = XFP + (size_t)(p * NB + b) * 8192;
  #pragma unroll
  for (int mt = 0; mt < 2; ++mt)
    #pragma unroll
    for (int nt = 0; nt < 4; ++nt)
      *(f32x4*)(op + (size_t)(nt * 16 + n) * 128 + (wv * 32 + mt * 16 + q * 4)) =
          acc[mt][nt];
}

// ---------------------------------------------------------------------------
// k1b: XFR = sum_p XFP[p] over 16 slabs. f32x4 lanes, coalesced.
// ---------------------------------------------------------------------------
__global__ __launch_bounds__(256) void k1b_red(const f32x4* __restrict__ XFP,
                                               f32x4* __restrict__ XFR) {
  const int idx = blockIdx.x * 256 + threadIdx.x;    // 65536 f32x4 total
  f32x4 s = XFP[idx];
  #pragma unroll
  for (int p = 1; p < SPLITK; ++p) {
    const f32x4 v = XFP[(size_t)p * 65536 + idx];
    s[0] += v[0]; s[1] += v[1]; s[2] += v[2]; s[3] += v[3];
  }
  XFR[idx] = s;
}

// ---------------------------------------------------------------------------
// kwc (fallback only, if d_ws unusable): wr -> WC copy so k2 can overwrite wr.
// ---------------------------------------------------------------------------
__global__ __launch_bounds__(256) void kwc_copy(const uint2* __restrict__ src,
                                                uint2* __restrict__ dst) {
  const int t = blockIdx.x * 256 + threadIdx.x;
  dst[t] = src[t];
  dst[t + 65536] = src[t + 65536];           // 131072 uint2 = 1 MiB
}

// ---------------------------------------------------------------------------
// k2 v3 (round-4 body): LDS-staged (straight contiguous copy of [c][2m] XFR),
// inner loop reads LDS float2 (2-way bank alias, free) + two global weight
// streams. Main path: weights straight from wr/wi inputs, TF into d_ws.
// ---------------------------------------------------------------------------
__global__ __launch_bounds__(256) void k2_mix(const float* __restrict__ XFR,
                                              const float* __restrict__ wre,
                                              const float* __restrict__ wi,
                                              const float* __restrict__ pww,
                                              uint32_t* __restrict__ tf_out) {
  const int b = blockIdx.x >> 3;
  const int og = blockIdx.x & 7;
  const int t = threadIdx.x;
  const int k = t & 63;                      // mode (lane)
  const int wv = t >> 6;
  __shared__ float sxf[8192];                // XFR[b] as-is: [c][2m], 32 KiB
  {
    f32x4* d = (f32x4*)sxf;
    const f32x4* s = (const f32x4*)(XFR + (size_t)b * 8192);
    #pragma unroll
    for (int i = 0; i < 8; ++i) d[t + i * 256] = s[t + i * 256];
  }
  __syncthreads();
  #pragma unroll
  for (int oo = 0; oo < 2; ++oo) {
    const int o = og * 8 + wv * 2 + oo;      // output channel
    float ar = 0.f, ai = 0.f;
    #pragma unroll 8
    for (int i = 0; i < 64; ++i) {           // input channel
      const float2 xv  = *(const float2*)&sxf[i * 128 + 2 * k];
      const float  wrv = wre[(size_t)i * 4096 + o * 64 + k];
      const float  wiv = wi[(size_t)i * 4096 + o * 64 + k];
      ar = fmaf(xv.x, wrv, ar);  ar = fmaf(-xv.y, wiv, ar);
      ai = fmaf(xv.x, wiv, ai);  ai = fmaf(xv.y, wrv, ai);
    }
    uint32_t* row = tf_out + ((size_t)b * 64 + o) * 96;
    row[k] = (uint32_t)f2bf(ar) | ((uint32_t)f2bf(ai) << 16);
    if (k < 32)                              // pw rows: bf16 pairs [64..96)
      row[64 + k] = (uint32_t)f2bf(pww[o * 64 + 2 * k]) |
                    ((uint32_t)f2bf(pww[o * 64 + 2 * k + 1]) << 16);
  }
}

// ---------------------------------------------------------------------------
// k3 v3 (round-4 best): TF staged into LDS (rows padded 192->200 bf16),
// all 8 pointwise x f32x4 loads hoisted to kernel entry, sincos spectral.
// ---------------------------------------------------------------------------
__global__ __launch_bounds__(256) void k3_out(const float* __restrict__ x,
                                              const unsigned short* __restrict__ tf,
                                              const float* __restrict__ bias,
                                              float* __restrict__ out) {
  const int b = blockIdx.x >> 6;
  const int lt = blockIdx.x & 63;
  const int t = threadIdx.x;
  const int wv = t >> 6;
  const int lane = t & 63;
  const int q = lane >> 4;
  const int n = lane & 15;
  const int l0 = lt * 128 + wv * 32;   // wave: 32 l-cols x 64 c-rows
  const float* xb = x + (size_t)b * L_ * NC;
  const unsigned short* tfb = tf + (size_t)b * 64 * 192;
  const float W0 = 6.283185307179586f / 8192.0f;
  const int lA = l0 + n;               // l for nt=0 (B-frag col = lane n)
  const int lB = l0 + 16 + n;          // l for nt=1

  // hoist pointwise x loads (consumed at s=4,5)
  const f32x4* pA0 = (const f32x4*)(xb + (size_t)lA * NC + q * 8);
  const f32x4* pB0 = (const f32x4*)(xb + (size_t)lB * NC + q * 8);
  const f32x4* pA1 = (const f32x4*)(xb + (size_t)lA * NC + 32 + q * 8);
  const f32x4* pB1 = (const f32x4*)(xb + (size_t)lB * NC + 32 + q * 8);
  const f32x4 xA00 = pA0[0], xA01 = pA0[1];
  const f32x4 xB00 = pB0[0], xB01 = pB0[1];
  const f32x4 xA10 = pA1[0], xA11 = pA1[1];
  const f32x4 xB10 = pB1[0], xB11 = pB1[1];

  // stage TF into LDS, rows padded 192 -> 200 bf16 (25.6 KiB)
  __shared__ unsigned short stf[64 * 200];
  {
    uint4* dst = (uint4*)stf;
    const uint4* src = (const uint4*)tfb;    // 1536 uint4 = 24 KiB
    #pragma unroll
    for (int i = 0; i < 6; ++i) {
      const int e4 = t + i * 256;
      const int row = e4 / 24, c4 = e4 - row * 24;   // 24 uint4 per 192-bf16 row
      dst[row * 25 + c4] = src[e4];                  // dst row stride 25 uint4
    }
  }
  __syncthreads();

  f32x4 acc[4][2];                     // [c-tile mt][l-tile nt]
  #pragma unroll
  for (int i = 0; i < 4; ++i)
    #pragma unroll
    for (int jn = 0; jn < 2; ++jn) acc[i][jn] = (f32x4){0.f, 0.f, 0.f, 0.f};

  #pragma unroll
  for (int s = 0; s < 6; ++s) {
    const int k0 = s * 32;
    bf16x8 b0, b1;
    if (s < 4) {                       // spectral: Bi[k][l] on the fly
      #pragma unroll
      for (int jj = 0; jj < 4; ++jj) {
        const int kf = (k0 >> 1) + q * 4 + jj;
        float sv, cv;
        __sincosf((float)((kf * lA) & 8191) * W0, &sv, &cv);
        b0[2 * jj] = (__bf16)cv; b0[2 * jj + 1] = (__bf16)(-sv);
        __sincosf((float)((kf * lB) & 8191) * W0, &sv, &cv);
        b1[2 * jj] = (__bf16)cv; b1[2 * jj + 1] = (__bf16)(-sv);
      }
    } else if (s == 4) {               // pointwise: hoisted x regs
      #pragma unroll
      for (int jj = 0; jj < 4; ++jj) {
        b0[jj] = (__bf16)xA00[jj]; b0[4 + jj] = (__bf16)xA01[jj];
        b1[jj] = (__bf16)xB00[jj]; b1[4 + jj] = (__bf16)xB01[jj];
      }
    } else {
      #pragma unroll
      for (int jj = 0; jj < 4; ++jj) {
        b0[jj] = (__bf16)xA10[jj]; b0[4 + jj] = (__bf16)xA11[jj];
        b1[jj] = (__bf16)xB10[jj]; b1[4 + jj] = (__bf16)xB11[jj];
      }
    }
    #pragma unroll
    for (int mt = 0; mt < 4; ++mt) {   // A-frag: TF row mt*16+n from LDS
      const bf16x8 afr = *(const bf16x8*)(stf + (mt * 16 + n) * 200 + k0 + q * 8);
      acc[mt][0] = mfma16(afr, b0, acc[mt][0]);
      acc[mt][1] = mfma16(afr, b1, acc[mt][1]);
    }
  }
  float* ob = out + (size_t)b * L_ * NC;
  #pragma unroll
  for (int mt = 0; mt < 4; ++mt) {
    const f32x4 bv = *(const f32x4*)(bias + mt * 16 + q * 4);
    #pragma unroll
    for (int nt = 0; nt < 2; ++nt) {
      const int l = l0 + nt * 16 + n;
      f32x4 v = acc[mt][nt];
      v[0] += bv[0]; v[1] += bv[1]; v[2] += bv[2]; v[3] += bv[3];
      *(f32x4*)(ob + (size_t)l * NC + mt * 16 + q * 4) = v;
    }
  }
}

// ---------------------------------------------------------------------------
extern "C" void kernel_launch(void* const* d_in, const int* in_sizes, int n_in,
                              void* d_out, int out_size, void* d_ws, size_t ws_size,
                              hipStream_t stream) {
  (void)in_sizes; (void)n_in; (void)out_size;
  const float* x    = (const float*)d_in[0];
  float*       wr   = (float*)d_in[1];
  const float* wi   = (const float*)d_in[2];
  const float* pww  = (const float*)d_in[3];
  const float* bias = (const float*)d_in[4];
  float* out = (float*)d_out;

  char* ob = (char*)d_out;
  float* XFP = (float*)(ob + XF_OFF);
  float* XFR = (float*)(ob + XR_OFF);
  float* WC  = (float*)(ob + WC_OFF);

  // Main path: TF in d_ws (proven >= 2 MiB, writable). Fallback: copy wr to
  // WC and reuse wr as the TF home (round-4 scheme).
  const bool useWs = (d_ws != nullptr) && (ws_size >= (size_t)(768u * 1024u));
  uint32_t* TFS = useWs ? (uint32_t*)d_ws : (uint32_t*)wr;
  const float* wsrc = useWs ? wr : WC;

  if (!useWs) kwc_copy<<<256, 256, 0, stream>>>((const uint2*)wr, (uint2*)WC);
  k1_dft  <<<NB * SPLITK, 256, 0, stream>>>(x, XFP);
  k1b_red <<<256,         256, 0, stream>>>((const f32x4*)XFP, (f32x4*)XFR);
  k2_mix  <<<NB * 8,      256, 0, stream>>>(XFR, wsrc, wi, pww, TFS);
  k3_out  <<<NB * 64,     256, 0, stream>>>(x, (const unsigned short*)TFS, bias, out);
}